// Round 10
// baseline (159.201 us; speedup 1.0000x reference)
//
#include <hip/hip_runtime.h>

// SSIM loss v17: LDS-free (v16 structure) + tap-axis VOP3P packing.
// v16 post-mortem: removing LDS cut stalls 306->~270 cyc/step (VALUBusy
// 58->66%) but lost the v2-packed horizontal (separate a/b windows -> 7
// scalar inst/tap vs v12's 4 packed) => issue +115 cyc/step, net loss.
// v17 packs along the TAP axis instead of the image axis: the 12-float
// window already sits in v4f regs = aligned VGPR pairs, so 6 v2 pairs
// (a0.xy, a0.zw, ...) x packed weight pairs wp[6] run all 5 chains as
// packed accumulators: 7 pk-inst per 2 taps = 3.5/tap (v12: 4, v16: 7).
// Horizontal 84 -> 41 pk + 10 combine. Ring/retire/shift/prefetch/wgm edge
// fold byte-identical to v16.
// Predicted: VALU issue -80 cyc/step, stall ~270 (unchanged structure),
// kernel 75 -> 60-65us; VGPR ~80-100, WRITE_SIZE ~24KB (spill tripwire).

#define BATCH  16
#define CHAN   3
#define H_     512
#define W_     512
#define HW     (H_ * W_)
#define CH_H   64
#define NSTEP  (CH_H + 10)          // 74
#define NPIX   ((long)BATCH*CHAN*H_*W_)

// Normalized 11-tap Gaussian, sigma=1.5 (constants gave absmax 0 in v1/v2/v6).
#define GW0 0.0010284f
#define GW1 0.0075988f
#define GW2 0.0360008f
#define GW3 0.1093554f
#define GW4 0.2130056f
#define GW5 0.2660117f

typedef float v2  __attribute__((ext_vector_type(2)));
typedef float v4f __attribute__((ext_vector_type(4)));

__device__ __forceinline__ v2 pfma(v2 a, v2 b, v2 c) {
#if __has_builtin(__builtin_elementwise_fma)
    return __builtin_elementwise_fma(a, b, c);
#else
    v2 r; r.x = fmaf(a.x, b.x, c.x); r.y = fmaf(a.y, b.y, c.y); return r;
#endif
}
__device__ __forceinline__ v2 psfma(float s, v2 b, v2 c) {  // (s,s)*b + c
    v2 sv; sv.x = s; sv.y = s;
    return pfma(sv, b, c);
}

__device__ __forceinline__ float wgk(int k) {  // k literal -> constant
    return (k == 0 || k == 10) ? GW0
         : (k == 1 || k == 9)  ? GW1
         : (k == 2 || k == 8)  ? GW2
         : (k == 3 || k == 7)  ? GW3
         : (k == 4 || k == 6)  ? GW4 : GW5;
}

__device__ __forceinline__ float ssim_retire(float mu1, float mu2,
                                             float x11, float x22, float x12) {
    const float c1 = 1.0e-4f;
    const float c2 = 9.0e-4f;
    float mu1s = mu1 * mu1;
    float mu2s = mu2 * mu2;
    float m12  = mu1 * mu2;
    float num  = (2.0f * m12 + c1) * (2.0f * (x12 - m12) + c2);
    float den  = (mu1s + mu2s + c1) * ((x11 - mu1s) + (x22 - mu2s) + c2);
#if __has_builtin(__builtin_amdgcn_rcpf)
    float l = 1.0f - num * __builtin_amdgcn_rcpf(den);   // v_rcp_f32, ~1 ulp
#else
    float l = 1.0f - num / den;
#endif
    return fminf(fmaxf(l, 0.0f), 1.0f);
}

// Slot i state: P=(mu1,mu2) packed, Q=(x11,x22) packed, E=x12 scalar.
#define DECL(i) v2 P##i = {0.f, 0.f}, Q##i = {0.f, 0.f}; float E##i = 0.f
#define ACCI(i) do { const float wj_ = wgk(10 - (i));            \
    P##i = psfma(wj_, hmm, P##i);                                \
    Q##i = psfma(wj_, hss, Q##i);                                \
    E##i = fmaf(wj_, hmx, E##i); } while (0)
#define SHIFT(i, j) P##i = P##j; Q##i = Q##j; E##i = E##j

// Packed-pair horizontal tap: pair p of window (pa_, pb_), weight pair wp_.
#define HPAIR(pa_, pb_, wp_) do {                                \
    v2 ta_ = (wp_) * (pa_);                                      \
    v2 tb_ = (wp_) * (pb_);                                      \
    hm1p += ta_;  hm2p += tb_;                                   \
    hm11p = pfma(ta_, (pa_), hm11p);                             \
    hm22p = pfma(tb_, (pb_), hm22p);                             \
    hm12p = pfma(ta_, (pb_), hm12p); } while (0)

__global__ __launch_bounds__(256) void ssim_kernel(const float* __restrict__ img1,
                                                   const float* __restrict__ img2,
                                                   float* __restrict__ out) {
    __shared__ float wsum[4];

    const int tid  = threadIdx.x;
    const int lane = tid & 63;
    const int wv   = tid >> 6;

    const int wid   = blockIdx.x * 4 + wv;     // 0..3071
    const int plane = wid >> 6;
    const int rem   = wid & 63;
    const int strip = rem & 7;
    const int chunk = rem >> 3;
    const int y0 = chunk * CH_H;
    const int c0 = strip * 64;

    // Lane owns output col (c0+lane); window cols bc..bc+10, bc = c0+lane-5.
    // Load base clamped to [0, W-12]; shift s = bcc-bc folds into the weight
    // index (float j of the window has weight wg(j+s) if valid else 0),
    // exactly reproducing zero-padding at both edges. Verified in v16.
    const int bc  = c0 + lane - 5;
    const int bcc = min(max(bc, 0), W_ - 12);
    const int s   = bcc - bc;                  // -6..5
    float wgm[12];
#pragma unroll
    for (int j = 0; j < 12; ++j) {
        int ki = j + s;
        float w = 0.0f;
        w = (ki == 0 || ki == 10) ? GW0 : w;
        w = (ki == 1 || ki == 9)  ? GW1 : w;
        w = (ki == 2 || ki == 8)  ? GW2 : w;
        w = (ki == 3 || ki == 7)  ? GW3 : w;
        w = (ki == 4 || ki == 6)  ? GW4 : w;
        w = (ki == 5)             ? GW5 : w;
        wgm[j] = w;
    }
    // Packed weight pairs (6 aligned v2 regs).
    const v2 wp0 = {wgm[0], wgm[1]},  wp1 = {wgm[2], wgm[3]};
    const v2 wp2 = {wgm[4], wgm[5]},  wp3 = {wgm[6], wgm[7]};
    const v2 wp4 = {wgm[8], wgm[9]},  wp5 = {wgm[10], wgm[11]};

    const size_t pb = (size_t)plane * HW;
    const float* __restrict__ p1 = img1 + pb + bcc;
    const float* __restrict__ p2 = img2 + pb + bcc;

    DECL(0); DECL(1); DECL(2); DECL(3); DECL(4); DECL(5);
    DECL(6); DECL(7); DECL(8); DECL(9); DECL(10);
    float lsum = 0.0f;

    // Current window regs (row y0+step-5) and its row mask.
    v4f a0, a1, a2, b0, b1, b2;
    float rmC;
    {
        int r = y0 - 5;
        rmC = ((unsigned)r < (unsigned)H_) ? 1.0f : 0.0f;
        size_t off = (size_t)((unsigned)r < (unsigned)H_ ? r : 0) << 9;
        a0 = *(const v4f*)(p1 + off);
        a1 = *(const v4f*)(p1 + off + 4);
        a2 = *(const v4f*)(p1 + off + 8);
        b0 = *(const v4f*)(p2 + off);
        b1 = *(const v4f*)(p2 + off + 4);
        b2 = *(const v4f*)(p2 + off + 8);
    }

#pragma unroll 2
    for (int step = 0; step < NSTEP; ++step) {
        const int yy = step - 10;              // output row retired this step

        // 1. Prefetch next row's windows (row y0+step-4); ~1 step of slack.
        v4f na0, na1, na2, nb0, nb1, nb2;
        float rmN;
        {
            int r = y0 + step - 4;
            bool rok = (unsigned)r < (unsigned)H_;
            rmN = rok ? 1.0f : 0.0f;
            size_t off = (size_t)(rok ? r : 0) << 9;
            na0 = *(const v4f*)(p1 + off);
            na1 = *(const v4f*)(p1 + off + 4);
            na2 = *(const v4f*)(p1 + off + 8);
            nb0 = *(const v4f*)(p2 + off);
            nb1 = *(const v4f*)(p2 + off + 4);
            nb2 = *(const v4f*)(p2 + off + 8);
        }

        // 2. Horizontal 12 taps as 6 packed pairs; 5 packed chains.
        //    Window pairs are v4f halves = aligned VGPR pairs (VOP3P-ready).
        v2 pa0 = {a0.x, a0.y}, pa1 = {a0.z, a0.w};
        v2 pa2 = {a1.x, a1.y}, pa3 = {a1.z, a1.w};
        v2 pa4 = {a2.x, a2.y}, pa5 = {a2.z, a2.w};
        v2 pb0 = {b0.x, b0.y}, pb1 = {b0.z, b0.w};
        v2 pb2 = {b1.x, b1.y}, pb3 = {b1.z, b1.w};
        v2 pb4 = {b2.x, b2.y}, pb5 = {b2.z, b2.w};

        v2 hm1p, hm2p, hm11p, hm22p, hm12p;
        {   // pair 0 initializes the chains (no zero-init adds)
            v2 ta_ = wp0 * pa0;
            v2 tb_ = wp0 * pb0;
            hm1p = ta_; hm2p = tb_;
            hm11p = ta_ * pa0;
            hm22p = tb_ * pb0;
            hm12p = ta_ * pb0;
        }
        HPAIR(pa1, pb1, wp1); HPAIR(pa2, pb2, wp2); HPAIR(pa3, pb3, wp3);
        HPAIR(pa4, pb4, wp4); HPAIR(pa5, pb5, wp5);

        // Combine packed halves; fold uniform row mask (10 scalar ops).
        v2 hmm = {(hm1p.x + hm1p.y) * rmC, (hm2p.x + hm2p.y) * rmC};
        v2 hss = {(hm11p.x + hm11p.y) * rmC, (hm22p.x + hm22p.y) * rmC};
        float hmx = (hm12p.x + hm12p.y) * rmC;

        // 3. Accumulate into the 11 in-flight output rows.
        ACCI(0); ACCI(1); ACCI(2); ACCI(3); ACCI(4); ACCI(5);
        ACCI(6); ACCI(7); ACCI(8); ACCI(9); ACCI(10);

        // 4. Retire output row yy (slot 0 complete).
        if (yy >= 0) lsum += ssim_retire(P0.x, P0.y, Q0.x, Q0.y, E0);

        // 5. Shift the register ring (pure SSA renames; unroll-2 elides half).
        SHIFT(0, 1); SHIFT(1, 2); SHIFT(2, 3); SHIFT(3, 4); SHIFT(4, 5);
        SHIFT(5, 6); SHIFT(6, 7); SHIFT(7, 8); SHIFT(8, 9); SHIFT(9, 10);
        P10 = (v2){0.f, 0.f}; Q10 = (v2){0.f, 0.f}; E10 = 0.f;

        // 6. Advance window pipeline (renames away under unroll-2).
        a0 = na0; a1 = na1; a2 = na2;
        b0 = nb0; b1 = nb1; b2 = nb2;
        rmC = rmN;
    }

    // Reduction: wave shuffle -> LDS -> one atomic per block.
#pragma unroll
    for (int off = 32; off > 0; off >>= 1) lsum += __shfl_down(lsum, off);
    if (lane == 0) wsum[wv] = lsum;
    __syncthreads();
    if (tid == 0) {
        float bs = wsum[0] + wsum[1] + wsum[2] + wsum[3];
        atomicAdd(out, bs * (0.5f / (float)NPIX));
    }
}

extern "C" void kernel_launch(void* const* d_in, const int* in_sizes, int n_in,
                              void* d_out, int out_size, void* d_ws, size_t ws_size,
                              hipStream_t stream) {
    const float* img1 = (const float*)d_in[0];
    const float* img2 = (const float*)d_in[1];
    float* out = (float*)d_out;

    hipMemsetAsync(out, 0, sizeof(float), stream);

    // 8 strips x 8 chunks x 48 planes = 3072 waves = 768 blocks = 3/CU.
    ssim_kernel<<<dim3(8 * 8 * BATCH * CHAN / 4), 256, 0, stream>>>(img1, img2, out);
}